// Round 3
// baseline (116.451 us; speedup 1.0000x reference)
//
#include <hip/hip_runtime.h>
#include <hip/hip_bf16.h>
#include <math.h>

// ---------------------------------------------------------------------------
// PointerNet attention scorer, MI355X / gfx950.
// Pipeline:
//   1) convert_hilo: fp32 -> bf16 hi/lo planes for src/query/W (row: [hi|lo])
//   2) proj_gemm:   C = scale*(A@W^T + bias) as ONE bf16 MFMA GEMM over a
//      K-pair list (hiA*hiW + hiA*loW + loA*hiW, rel err ~2^-16).
//      m97-style global_load_lds staging, XOR-swizzled LDS, double-buffered.
//      z(src): store h-quad-interleaved spq; z(query): row-major qp.
//   3) attn_score:  logit ~ -2*sum_h w2/(exp2(sp'+qp')+1)  (shift-invariant
//      terms dropped), masked softmax over S. 512 thr, H split 4-ways.
// ---------------------------------------------------------------------------

#define TANH_PRESCALE 2.8853900817779268f   // 2*log2(e)
#define LOG2E        1.4426950408889634f

typedef __attribute__((ext_vector_type(8))) short short8;   // 8 bf16 = 4 VGPR
typedef __attribute__((ext_vector_type(4))) float f32x4;    // MFMA C/D frag

__device__ __forceinline__ float fast_exp2(float x) {
#if __has_builtin(__builtin_amdgcn_exp2f)
    return __builtin_amdgcn_exp2f(x);
#else
    return exp2f(x);
#endif
}
__device__ __forceinline__ float fast_rcp(float x) {
#if __has_builtin(__builtin_amdgcn_rcpf)
    return __builtin_amdgcn_rcpf(x);
#else
    return 1.0f / x;
#endif
}
__device__ __forceinline__ float hi_part(float x) {   // truncate to bf16 grid
    return __uint_as_float(__float_as_uint(x) & 0xffff0000u);
}
// pack bf16(a)=low16, bf16(b)=high16 (truncating) in one v_perm
__device__ __forceinline__ unsigned pack2(float a, float b) {
    return __builtin_amdgcn_perm(__float_as_uint(b), __float_as_uint(a), 0x07060302u);
}
// async global->LDS, 16B per lane (CK-style addrspace casts)
__device__ __forceinline__ void async16(const void* g, void* l) {
    __builtin_amdgcn_global_load_lds(
        (const __attribute__((address_space(1))) unsigned int*)(unsigned long long)g,
        (__attribute__((address_space(3))) unsigned int*)(unsigned int)(unsigned long long)l,
        16, 0, 0);
}

// ---------------------------------------------------------------------------
// 1) fp32 -> bf16 hi/lo. Out row layout (1024 bf16): [k:hi 0..511 | k:lo 0..511]
// blocks: 0..511 src(4096r), 512..767 query(2048r, appended to Ah),
//         768..799 W_src(256r), 800..831 W_q(256r). 8 rows/block.
// ---------------------------------------------------------------------------
__global__ __launch_bounds__(256) void convert_hilo(
    const float* __restrict__ src, const float* __restrict__ query,
    const float* __restrict__ Wsrc, const float* __restrict__ Wq,
    unsigned short* __restrict__ Ah, unsigned short* __restrict__ Wsh,
    unsigned short* __restrict__ Wqh)
{
    const int b = blockIdx.x;
    const float* in; unsigned short* out; int r0;
    if (b < 512)      { in = src;   out = Ah;                      r0 = b * 8; }
    else if (b < 768) { in = query; out = Ah + (size_t)4096 * 1024; r0 = (b - 512) * 8; }
    else if (b < 800) { in = Wsrc;  out = Wsh;                     r0 = (b - 768) * 8; }
    else              { in = Wq;    out = Wqh;                     r0 = (b - 800) * 8; }
    in  += (size_t)r0 * 512;
    out += (size_t)r0 * 1024;
    const int tid = threadIdx.x;
    #pragma unroll
    for (int i = 0; i < 4; ++i) {
        const int idx = i * 256 + tid;          // 1024 float4s per block
        const int row = idx >> 7, k4 = idx & 127;
        float4 v = *(const float4*)(in + (size_t)row * 512 + k4 * 4);
        unsigned h0 = pack2(v.x, v.y), h1 = pack2(v.z, v.w);
        float lx = v.x - hi_part(v.x), ly = v.y - hi_part(v.y);
        float lz = v.z - hi_part(v.z), lw = v.w - hi_part(v.w);
        unsigned l0 = pack2(lx, ly), l1 = pack2(lz, lw);
        *(uint2*)(out + (size_t)row * 1024 + k4 * 4)       = make_uint2(h0, h1);
        *(uint2*)(out + (size_t)row * 1024 + 512 + k4 * 4) = make_uint2(l0, l1);
    }
}

// ---------------------------------------------------------------------------
// 2) MFMA GEMM. Tile 128m x 64n, 128 thr (2 waves), wave = 64m x 64n
// (4x4 16x16x32 frags). K-pair list: 24 tiles of BK=64 over the hi/lo planes.
// LDS (unpadded, required by global_load_lds) uses XOR swizzle:
//   slot(row, j) holds physical k-octet j ^ (row & 7)  -> frag reads 2-way.
// Double-buffered: stage(p+1) issued before compute(p); barrier's vmcnt(0)
// drain provides the handoff.
// ---------------------------------------------------------------------------
__global__ __launch_bounds__(128) void proj_gemm(
    const unsigned short* __restrict__ Ah,
    const unsigned short* __restrict__ Wsh, const unsigned short* __restrict__ Wqh,
    const float* __restrict__ b_src, const float* __restrict__ b_q,
    float* __restrict__ spq, float* __restrict__ qp)
{
    const int bx = blockIdx.x;       // 0..47 (0..31 src, 32..47 query)
    const int nb = blockIdx.y;       // 0..3
    const bool isSrc = bx < 32;
    const int mrow0 = isSrc ? bx * 128 : (bx - 32) * 128;  // row within matrix
    const size_t arow0 = isSrc ? (size_t)bx * 128
                               : (size_t)4096 + (size_t)(bx - 32) * 128;
    const unsigned short* Wm = isSrc ? Wsh : Wqh;
    const float* bias = isSrc ? b_src : b_q;

    __shared__ char LB[49152];   // A: 2x16KB @0,16384 ; W: 2x8KB @32768,40960

    const int tid  = threadIdx.x;
    const int lane = tid & 63;
    const int wv   = tid >> 6;        // 0..1
    const int l15  = lane & 15;
    const int l4q  = lane >> 4;       // 0..3

    // staging lane constants: lane L covers (row srow, LDS slot L&7),
    // fetching physical k-octet (L&7) ^ (srow&7)
    const int srow = lane >> 3;                       // 0..7
    const int ssw  = (lane & 7) ^ (srow & 7);
    const size_t g_lane = (size_t)srow * 2048 + (size_t)ssw * 16;  // bytes
    const char* Agbase = (const char*)(Ah + arow0 * 1024);
    const char* Wgbase = (const char*)(Wm + (size_t)(nb * 64) * 1024);

    f32x4 acc[4][4];
    #pragma unroll
    for (int i = 0; i < 4; ++i)
        #pragma unroll
        for (int j = 0; j < 4; ++j) acc[i][j] = (f32x4){0.f, 0.f, 0.f, 0.f};

    // K-pair tables: p<16 even: (hi t, hi t); p<16 odd: (hi t, lo t); p>=16: (lo t, hi t)
    #define STAGE(p, buf) {                                                     \
        const int t_  = ((p) < 16) ? ((p) >> 1) : ((p) - 16);                   \
        const int ka_ = ((p) < 16) ? t_ * 64 : 512 + t_ * 64;                   \
        const int kw_ = ((p) < 16) ? (((p) & 1) ? 512 + t_ * 64 : t_ * 64)      \
                                   : t_ * 64;                                   \
        const char* ag = Agbase + (size_t)ka_ * 2 + g_lane;                     \
        char* al = LB + (buf) * 16384 + (wv * 64) * 128 + lane * 16;            \
        _Pragma("unroll")                                                       \
        for (int i_ = 0; i_ < 8; ++i_)                                          \
            async16(ag + (size_t)(wv * 64 + i_ * 8) * 2048, al + i_ * 1024);    \
        const char* wg = Wgbase + (size_t)kw_ * 2 + g_lane;                     \
        char* wl = LB + 32768 + (buf) * 8192 + (wv * 32) * 128 + lane * 16;     \
        _Pragma("unroll")                                                       \
        for (int i_ = 0; i_ < 4; ++i_)                                          \
            async16(wg + (size_t)(wv * 32 + i_ * 8) * 2048, wl + i_ * 1024);    \
    }

    STAGE(0, 0)
    for (int p = 0; p < 24; ++p) {
        __syncthreads();                       // buf[p&1] staged; prev compute done
        if (p + 1 < 24) STAGE(p + 1, (p + 1) & 1)
        const char* At = LB + (p & 1) * 16384;
        const char* Wt = LB + 32768 + (p & 1) * 8192;
        #pragma unroll
        for (int kk = 0; kk < 2; ++kk) {
            short8 af[4], wf[4];
            #pragma unroll
            for (int mi = 0; mi < 4; ++mi) {
                const int r = wv * 64 + mi * 16 + l15;
                const int j = (kk * 4 + l4q) ^ (r & 7);
                af[mi] = *(const short8*)(At + r * 128 + j * 16);
            }
            #pragma unroll
            for (int ni = 0; ni < 4; ++ni) {
                const int r = ni * 16 + l15;
                const int j = (kk * 4 + l4q) ^ (r & 7);
                wf[ni] = *(const short8*)(Wt + r * 128 + j * 16);
            }
            #pragma unroll
            for (int mi = 0; mi < 4; ++mi)
                #pragma unroll
                for (int ni = 0; ni < 4; ++ni)
                    acc[mi][ni] = __builtin_amdgcn_mfma_f32_16x16x32_bf16(
                        af[mi], wf[ni], acc[mi][ni], 0, 0, 0);
        }
    }

    float bl[4];
    #pragma unroll
    for (int ni = 0; ni < 4; ++ni) bl[ni] = bias[nb * 64 + ni * 16 + l15];

    __syncthreads();                 // all ds_reads done before E overwrites LDS
    float* E = (float*)LB;           // 128 x 68 fp32 = 34816 B
    #pragma unroll
    for (int mi = 0; mi < 4; ++mi)
        #pragma unroll
        for (int ni = 0; ni < 4; ++ni) {
            const int m = wv * 64 + mi * 16 + l4q * 4;
            const int n = ni * 16 + l15;
            #pragma unroll
            for (int r = 0; r < 4; ++r)
                E[(m + r) * 68 + n] = (acc[mi][ni][r] + bl[ni]) * TANH_PRESCALE;
        }
    __syncthreads();

    if (isSrc) {   // h-quad-interleaved: spq[(nb*16+nq)*16384 + (mrow0+m)*4 + (n&3)]
        #pragma unroll
        for (int p2 = 0; p2 < 4; ++p2) {
            const int nq = (tid >> 5) + 4 * p2;          // 0..15
            #pragma unroll
            for (int j = 0; j < 4; ++j) {
                const int m = (tid & 31) + 32 * j;       // 0..127
                float4 v = *(const float4*)&E[m * 68 + nq * 4];
                *(float4*)(spq + (size_t)(nb * 16 + nq) * 16384
                               + (size_t)(mrow0 + m) * 4) = v;
            }
        }
    } else {       // row-major qp[(mrow0+m)*256 + nb*64 + n]
        #pragma unroll
        for (int it = 0; it < 16; ++it) {
            const int m = (tid >> 4) + 8 * it;           // 0..127
            const int n4 = tid & 15;
            float4 v = *(const float4*)&E[m * 68 + n4 * 4];
            *(float4*)(qp + (size_t)(mrow0 + m) * 256 + nb * 64 + n4 * 4) = v;
        }
    }
}

// ---------------------------------------------------------------------------
// 3) Fused score + masked softmax. Block = (b, 4-t chunk), 512 thr (8 waves).
// Thread (s, h-group g of 64) carries 4 t-accumulators; partials combined in
// LDS; per-wave softmax over S=128 in waves 0..3.
// ---------------------------------------------------------------------------
__global__ __launch_bounds__(512) void attn_score(
    const float* __restrict__ spq, const float* __restrict__ qp,
    const float* __restrict__ w2, const int* __restrict__ mask,
    float* __restrict__ out)
{
    const int b  = blockIdx.x;   // 0..31
    const int tz = blockIdx.y;   // 0..15
    const int tid = threadIdx.x;

    __shared__ float qp_s[4][256];
    __shared__ float w2_s[256];
    __shared__ float h2p[4][4][128];   // [h-group][t-local][s]

    if (tid < 256) {
        const int tl = tid >> 6, lane = tid & 63;
        const int t = tz * 4 + tl;
        *(float4*)&qp_s[tl][lane * 4] =
            *(const float4*)(qp + (size_t)(t * 32 + b) * 256 + lane * 4);
    } else if (tid < 320) {
        const int i = tid - 256;
        *(float4*)&w2_s[i * 4] = *(const float4*)(w2 + i * 4);
    }
    __syncthreads();

    const int s = tid & 127;
    const int g = tid >> 7;            // 0..3 -> h in [g*64, g*64+64)
    const int hb = g * 64;
    const float* sq = spq + (size_t)(g * 16) * 16384 + (size_t)(b * 128 + s) * 4;

    float acc0 = 0.f, acc1 = 0.f, acc2 = 0.f, acc3 = 0.f;
    #pragma unroll 4
    for (int hq = 0; hq < 16; ++hq) {
        float4 s4 = *(const float4*)(sq + (size_t)hq * 16384);
        float4 w4 = *(const float4*)&w2_s[hb + hq * 4];
        float4 q0 = *(const float4*)&qp_s[0][hb + hq * 4];
        float4 q1 = *(const float4*)&qp_s[1][hb + hq * 4];
        float4 q2 = *(const float4*)&qp_s[2][hb + hq * 4];
        float4 q3 = *(const float4*)&qp_s[3][hb + hq * 4];
        #define PN_TERM(sj, wj, q0j, q1j, q2j, q3j)                              \
            { float r;                                                           \
              r = fast_rcp(fast_exp2(sj + q0j) + 1.0f); acc0 = fmaf(wj, r, acc0);\
              r = fast_rcp(fast_exp2(sj + q1j) + 1.0f); acc1 = fmaf(wj, r, acc1);\
              r = fast_rcp(fast_exp2(sj + q2j) + 1.0f); acc2 = fmaf(wj, r, acc2);\
              r = fast_rcp(fast_exp2(sj + q3j) + 1.0f); acc3 = fmaf(wj, r, acc3); }
        PN_TERM(s4.x, w4.x, q0.x, q1.x, q2.x, q3.x)
        PN_TERM(s4.y, w4.y, q0.y, q1.y, q2.y, q3.y)
        PN_TERM(s4.z, w4.z, q0.z, q1.z, q2.z, q3.z)
        PN_TERM(s4.w, w4.w, q0.w, q1.w, q2.w, q3.w)
        #undef PN_TERM
    }
    h2p[g][0][s] = acc0;
    h2p[g][1][s] = acc1;
    h2p[g][2][s] = acc2;
    h2p[g][3][s] = acc3;
    __syncthreads();

    if (tid < 256) {
        const int wv = tid >> 6, lane = tid & 63;
        float v0 = -2.0f * (h2p[0][wv][lane] + h2p[1][wv][lane]
                          + h2p[2][wv][lane] + h2p[3][wv][lane]);
        float v1 = -2.0f * (h2p[0][wv][lane + 64] + h2p[1][wv][lane + 64]
                          + h2p[2][wv][lane + 64] + h2p[3][wv][lane + 64]);
        if (mask[b * 128 + lane])      v0 = -__builtin_inff();
        if (mask[b * 128 + lane + 64]) v1 = -__builtin_inff();

        float mx = fmaxf(v0, v1);
        #pragma unroll
        for (int off = 32; off >= 1; off >>= 1) mx = fmaxf(mx, __shfl_xor(mx, off));
        float e0 = fast_exp2((v0 - mx) * LOG2E);   // -inf -> 0
        float e1 = fast_exp2((v1 - mx) * LOG2E);
        float sum = e0 + e1;
        #pragma unroll
        for (int off = 32; off >= 1; off >>= 1) sum += __shfl_xor(sum, off);
        const float r = fast_rcp(sum);

        const size_t ob = (size_t)((tz * 4 + wv) * 32 + b) * 128;
        out[ob + lane]      = e0 * r;
        out[ob + lane + 64] = e1 * r;
    }
}

extern "C" void kernel_launch(void* const* d_in, const int* in_sizes, int n_in,
                              void* d_out, int out_size, void* d_ws, size_t ws_size,
                              hipStream_t stream) {
    const float* src   = (const float*)d_in[0];   // (B,S,E)
    const int*   mask  = (const int*)  d_in[1];   // (B,S)
    const float* query = (const float*)d_in[2];   // (T,B,Q)
    const float* W_src = (const float*)d_in[3];   // (H,E)
    const float* b_src = (const float*)d_in[4];
    const float* W_q   = (const float*)d_in[5];   // (H,Q)
    const float* b_q   = (const float*)d_in[6];
    const float* w2    = (const float*)d_in[7];
    // d_in[8] = b2 : unused (softmax shift-invariant)
    float* out = (float*)d_out;

    // ws layout (bytes): spq 0..4MB | qp 4..6MB | Ah 6..18MB | Wsh | Wqh
    float* spq = (float*)d_ws;
    float* qp  = (float*)((char*)d_ws + (4u << 20));
    unsigned short* Ah  = (unsigned short*)((char*)d_ws + (6u << 20));
    unsigned short* Wsh = (unsigned short*)((char*)d_ws + 18874368u);
    unsigned short* Wqh = (unsigned short*)((char*)d_ws + 19398656u);

    convert_hilo<<<832, 256, 0, stream>>>(src, query, W_src, W_q, Ah, Wsh, Wqh);
    proj_gemm<<<dim3(48, 4), 128, 0, stream>>>(Ah, Wsh, Wqh, b_src, b_q, spq, qp);
    attn_score<<<dim3(32, 16), 512, 0, stream>>>(spq, qp, w2, mask, out);
}